// Round 1
// baseline (79.076 us; speedup 1.0000x reference)
//
#include <hip/hip_runtime.h>
#include <hip/hip_bf16.h>

#define BB 4
#define TT 2048
#define DD 128
#define CHK 64
#define NCHK 32           // TT / CHK
#define NROWS (BB*TT)     // 8192

// ---------------------------------------------------------------------------
// Kernel 1: Qf = phi(q) = ELU(q @ W^T + b) + 1 ; same for Kf = phi(k).
// grid: 2 * (NROWS/8) blocks of 128 threads; each block does 8 rows x 128 cols.
// ---------------------------------------------------------------------------
__global__ __launch_bounds__(128) void phi_kernel(const float* __restrict__ q,
                                                  const float* __restrict__ k,
                                                  const float* __restrict__ W,
                                                  const float* __restrict__ bias,
                                                  float* __restrict__ Qf,
                                                  float* __restrict__ Kf) {
    int blk = blockIdx.x;
    const int nblk_per = NROWS / 8;  // 1024
    const float* x;
    float* outp;
    if (blk < nblk_per) { x = q + (size_t)blk * 8 * DD;              outp = Qf + (size_t)blk * 8 * DD; }
    else                { int b2 = blk - nblk_per;
                          x = k + (size_t)b2 * 8 * DD;               outp = Kf + (size_t)b2 * 8 * DD; }

    __shared__ float xs[8][DD];
    int e = threadIdx.x;
    #pragma unroll
    for (int r = 0; r < 8; ++r) xs[r][e] = x[r * DD + e];
    __syncthreads();

    float acc[8];
    float bv = bias[e];
    #pragma unroll
    for (int r = 0; r < 8; ++r) acc[r] = bv;

    const float4* Wrow = reinterpret_cast<const float4*>(W + (size_t)e * DD);
    #pragma unroll 4
    for (int d4 = 0; d4 < DD / 4; ++d4) {
        float4 w = Wrow[d4];
        #pragma unroll
        for (int r = 0; r < 8; ++r) {
            acc[r] += w.x * xs[r][d4*4+0] + w.y * xs[r][d4*4+1]
                    + w.z * xs[r][d4*4+2] + w.w * xs[r][d4*4+3];
        }
    }
    #pragma unroll
    for (int r = 0; r < 8; ++r) {
        float zv = acc[r];
        outp[r * DD + e] = (zv > 0.f) ? (zv + 1.f) : __expf(zv);  // ELU(z)+1
    }
}

// ---------------------------------------------------------------------------
// Kernel 2: per-chunk sums.  S_c[d][e] = sum_tau Kf[tau][d] * v[tau][e],
//                            z_c[d]    = sum_tau Kf[tau][d].
// grid: BB*NCHK blocks of 256 threads; thread computes an 8x8 tile of [128x128].
// ---------------------------------------------------------------------------
__global__ __launch_bounds__(256) void chunksum_kernel(const float* __restrict__ Kf,
                                                       const float* __restrict__ v,
                                                       float* __restrict__ Ssum,
                                                       float* __restrict__ zsum) {
    int chunk = blockIdx.x;
    const float* Kc = Kf + (size_t)chunk * CHK * DD;
    const float* Vc = v  + (size_t)chunk * CHK * DD;

    __shared__ float ks[16][DD];
    __shared__ float vs[16][DD];

    int tid = threadIdx.x;
    int d0 = (tid / 16) * 8;
    int e0 = (tid % 16) * 8;

    float acc[8][8] = {{0.f}};
    float zacc[8]   = {0.f};

    for (int tt = 0; tt < CHK / 16; ++tt) {
        __syncthreads();
        for (int idx = tid; idx < 16 * DD / 4; idx += 256) {
            int r = idx / 32, c4 = (idx % 32) * 4;
            *(float4*)&ks[r][c4] = *(const float4*)(Kc + (tt * 16 + r) * DD + c4);
            *(float4*)&vs[r][c4] = *(const float4*)(Vc + (tt * 16 + r) * DD + c4);
        }
        __syncthreads();
        for (int tau = 0; tau < 16; ++tau) {
            float kk[8], vv[8];
            #pragma unroll
            for (int i = 0; i < 8; ++i) { kk[i] = ks[tau][d0 + i]; vv[i] = vs[tau][e0 + i]; }
            #pragma unroll
            for (int i = 0; i < 8; ++i) {
                zacc[i] += kk[i];
                #pragma unroll
                for (int j = 0; j < 8; ++j) acc[i][j] += kk[i] * vv[j];
            }
        }
    }

    float* Sc = Ssum + (size_t)chunk * DD * DD;
    #pragma unroll
    for (int i = 0; i < 8; ++i)
        #pragma unroll
        for (int j = 0; j < 8; ++j)
            Sc[(d0 + i) * DD + e0 + j] = acc[i][j];

    if (e0 == 0) {
        #pragma unroll
        for (int i = 0; i < 8; ++i) zsum[(size_t)chunk * DD + d0 + i] = zacc[i];
    }
}

// ---------------------------------------------------------------------------
// Kernel 3: in-place EXCLUSIVE prefix over chunks (per batch).
// grid: BB*DD blocks of 128 threads. Thread e scans S[b, :, d, e]; thread 0
// also scans z[b, :, d].
// ---------------------------------------------------------------------------
__global__ __launch_bounds__(128) void scan_kernel(float* __restrict__ Ssum,
                                                   float* __restrict__ zsum) {
    int b = blockIdx.x >> 7;
    int d = blockIdx.x & 127;
    int e = threadIdx.x;
    float run = 0.f;
    for (int c = 0; c < NCHK; ++c) {
        size_t idx = (((size_t)(b * NCHK + c) * DD) + d) * DD + e;
        float t = Ssum[idx];
        Ssum[idx] = run;
        run += t;
    }
    if (e == 0) {
        float rz = 0.f;
        for (int c = 0; c < NCHK; ++c) {
            size_t iz = (size_t)(b * NCHK + c) * DD + d;
            float t = zsum[iz];
            zsum[iz] = rz;
            rz += t;
        }
    }
}

// ---------------------------------------------------------------------------
// Kernel 4: per-chunk output.
//   A = Qf_c Kf_c^T (causal masked, diag included)
//   out = A @ V_c + Qf_c @ S_prefix
//   den = rowsum(A) + Qf_c . z_prefix + eps ; out /= den
// grid: BB*NCHK blocks of 256 threads.
// ---------------------------------------------------------------------------
__global__ __launch_bounds__(256) void out_kernel(const float* __restrict__ Qf,
                                                  const float* __restrict__ Kf,
                                                  const float* __restrict__ v,
                                                  const float* __restrict__ Spre,
                                                  const float* __restrict__ zpre,
                                                  float* __restrict__ out) {
    int chunk = blockIdx.x;
    const float* Qc = Qf + (size_t)chunk * CHK * DD;
    const float* Kc = Kf + (size_t)chunk * CHK * DD;
    const float* Vc = v  + (size_t)chunk * CHK * DD;
    const float* Sp = Spre + (size_t)chunk * DD * DD;
    const float* zp = zpre + (size_t)chunk * DD;
    float* outc = out + (size_t)chunk * CHK * DD;

    __shared__ float qs[CHK][DD + 1];   // pad 129: (i*129+d)%32 = (i+d)%32 spreads banks
    __shared__ float kv[CHK][DD + 1];   // holds K, then reloaded with V
    __shared__ float As[CHK][CHK + 1];  // pad 65
    __shared__ float st[16][DD];        // S_prefix d-tile
    __shared__ float zst[DD];
    __shared__ float den_s[CHK];

    int tid = threadIdx.x;

    for (int idx = tid; idx < CHK * DD / 4; idx += 256) {
        int r = idx / 32, c4 = (idx % 32) * 4;
        float4 qv = *(const float4*)(Qc + r * DD + c4);
        qs[r][c4+0] = qv.x; qs[r][c4+1] = qv.y; qs[r][c4+2] = qv.z; qs[r][c4+3] = qv.w;
        float4 kk = *(const float4*)(Kc + r * DD + c4);
        kv[r][c4+0] = kk.x; kv[r][c4+1] = kk.y; kv[r][c4+2] = kk.z; kv[r][c4+3] = kk.w;
    }
    if (tid < DD) zst[tid] = zp[tid];
    __syncthreads();

    int ti = tid / 16, te = tid % 16;
    int i0 = ti * 4;        // 4 output rows per thread (also A rows)
    int j0 = te * 4;        // 4 A cols per thread
    int e0 = te * 8;        // 8 output cols per thread

    // ---- Phase A: A = Q K^T, causal mask ----
    {
        float a[4][4] = {{0.f}};
        for (int d = 0; d < DD; ++d) {
            float qreg[4], kreg[4];
            #pragma unroll
            for (int r = 0; r < 4; ++r) { qreg[r] = qs[i0 + r][d]; kreg[r] = kv[j0 + r][d]; }
            #pragma unroll
            for (int r = 0; r < 4; ++r)
                #pragma unroll
                for (int c = 0; c < 4; ++c) a[r][c] += qreg[r] * kreg[c];
        }
        #pragma unroll
        for (int r = 0; r < 4; ++r)
            #pragma unroll
            for (int c = 0; c < 4; ++c) {
                int i = i0 + r, j = j0 + c;
                As[i][j] = (j <= i) ? a[r][c] : 0.f;
            }
    }
    __syncthreads();

    // ---- den (threads 0..63, one row each) ----
    if (tid < CHK) {
        int i = tid;
        float s = 1e-6f;
        for (int j = 0; j < CHK; ++j) s += As[i][j];     // masked beyond i
        float qz = 0.f;
        for (int d = 0; d < DD; ++d) qz += qs[i][d] * zst[d];
        den_s[i] = s + qz;
    }

    // ---- Phase B: inter-chunk, out += Q @ S_prefix ----
    float oacc[4][8] = {{0.f}};
    for (int dt = 0; dt < DD / 16; ++dt) {
        __syncthreads();
        for (int idx = tid; idx < 16 * DD / 4; idx += 256) {
            int r = idx / 32, c4 = (idx % 32) * 4;
            *(float4*)&st[r][c4] = *(const float4*)(Sp + (dt * 16 + r) * DD + c4);
        }
        __syncthreads();
        for (int dd = 0; dd < 16; ++dd) {
            float qreg[4];
            #pragma unroll
            for (int r = 0; r < 4; ++r) qreg[r] = qs[i0 + r][dt * 16 + dd];
            float4 sva = *(const float4*)&st[dd][e0];
            float4 svb = *(const float4*)&st[dd][e0 + 4];
            float sv[8] = {sva.x, sva.y, sva.z, sva.w, svb.x, svb.y, svb.z, svb.w};
            #pragma unroll
            for (int r = 0; r < 4; ++r)
                #pragma unroll
                for (int c = 0; c < 8; ++c) oacc[r][c] += qreg[r] * sv[c];
        }
    }

    // ---- Phase C: intra-chunk, out += A @ V (reload kv with V) ----
    __syncthreads();
    for (int idx = tid; idx < CHK * DD / 4; idx += 256) {
        int r = idx / 32, c4 = (idx % 32) * 4;
        float4 vv = *(const float4*)(Vc + r * DD + c4);
        kv[r][c4+0] = vv.x; kv[r][c4+1] = vv.y; kv[r][c4+2] = vv.z; kv[r][c4+3] = vv.w;
    }
    __syncthreads();
    for (int j = 0; j < CHK; ++j) {
        float a4[4], v8[8];
        #pragma unroll
        for (int r = 0; r < 4; ++r) a4[r] = As[i0 + r][j];
        #pragma unroll
        for (int c = 0; c < 8; ++c) v8[c] = kv[j][e0 + c];
        #pragma unroll
        for (int r = 0; r < 4; ++r)
            #pragma unroll
            for (int c = 0; c < 8; ++c) oacc[r][c] += a4[r] * v8[c];
    }

    // ---- divide by den, store ----
    #pragma unroll
    for (int r = 0; r < 4; ++r) {
        float inv = 1.0f / den_s[i0 + r];
        #pragma unroll
        for (int c = 0; c < 8; ++c)
            outc[(i0 + r) * DD + e0 + c] = oacc[r][c] * inv;
    }
}

// ---------------------------------------------------------------------------
extern "C" void kernel_launch(void* const* d_in, const int* in_sizes, int n_in,
                              void* d_out, int out_size, void* d_ws, size_t ws_size,
                              hipStream_t stream) {
    const float* q = (const float*)d_in[0];
    const float* k = (const float*)d_in[1];
    const float* v = (const float*)d_in[2];
    const float* W = (const float*)d_in[3];
    const float* b = (const float*)d_in[4];
    float* out = (float*)d_out;

    float* ws   = (float*)d_ws;
    float* Qf   = ws;                                  // BB*TT*DD       = 1,048,576 f
    float* Kf   = Qf + (size_t)BB * TT * DD;           // + 1,048,576 f
    float* Ssum = Kf + (size_t)BB * TT * DD;           // BB*NCHK*DD*DD  = 2,097,152 f
    float* zsum = Ssum + (size_t)BB * NCHK * DD * DD;  // BB*NCHK*DD     = 16,384 f
                                                       // total ~16.8 MB of ws

    phi_kernel<<<2 * (NROWS / 8), 128, 0, stream>>>(q, k, W, b, Qf, Kf);
    chunksum_kernel<<<BB * NCHK, 256, 0, stream>>>(Kf, v, Ssum, zsum);
    scan_kernel<<<BB * DD, 128, 0, stream>>>(Ssum, zsum);
    out_kernel<<<BB * NCHK, 256, 0, stream>>>(Qf, Kf, v, Ssum, zsum, out);
}

// Round 2
// 41.159 us; speedup vs baseline: 1.9212x; 1.9212x over previous
//
#include <hip/hip_runtime.h>
#include <hip/hip_bf16.h>

#define BB 4
#define TT 2048
#define DD 128
#define CHK 64
#define NCHK 32            // TT/CHK
#define NCHKS (BB*NCHK)    // 128 chunks total

typedef __attribute__((ext_vector_type(8))) short  bf16x8;
typedef __attribute__((ext_vector_type(4))) float  f32x4;

#define MFMA(a,b,c) __builtin_amdgcn_mfma_f32_16x16x32_bf16(a, b, c, 0, 0, 0)

__device__ __forceinline__ short f2b(float f) {
    union { float f; unsigned u; } x; x.f = f;
    unsigned r = x.u + 0x7fffu + ((x.u >> 16) & 1u);   // RNE
    return (short)(r >> 16);
}
__device__ __forceinline__ float b2f(short s) {
    union { unsigned u; float f; } x; x.u = ((unsigned)(unsigned short)s) << 16;
    return x.f;
}
// 8 consecutive fp32 -> bf16x8 fragment
__device__ __forceinline__ bf16x8 cvt8(const float* p) {
    float4 a = *(const float4*)p, b = *(const float4*)(p + 4);
    bf16x8 r;
    r[0]=f2b(a.x); r[1]=f2b(a.y); r[2]=f2b(a.z); r[3]=f2b(a.w);
    r[4]=f2b(b.x); r[5]=f2b(b.y); r[6]=f2b(b.z); r[7]=f2b(b.w);
    return r;
}

// ---------------------------------------------------------------------------
// K0: W fp32 [128][128] -> bf16
// ---------------------------------------------------------------------------
__global__ __launch_bounds__(256) void k0_convw(const float* __restrict__ W,
                                                short* __restrict__ Wb) {
    int i = blockIdx.x * 256 + threadIdx.x;           // 4096 float4s
    float4 v = *(const float4*)(W + i * 4);
    unsigned lo = (unsigned short)f2b(v.x) | ((unsigned)(unsigned short)f2b(v.y) << 16);
    unsigned hi = (unsigned short)f2b(v.z) | ((unsigned)(unsigned short)f2b(v.w) << 16);
    uint2 p; p.x = lo; p.y = hi;
    *(uint2*)(Wb + i * 4) = p;
}

// ---------------------------------------------------------------------------
// K1: per chunk c: Kf = phi(k_c) (MFMA); S_c^T = (Kf^T v)^T -> global fp32 [e][d];
//     z_c[d]; vT_c bf16 [e][t] -> global.
// grid 128 blocks x 256 thr (4 waves; wave = 16-row strip of phi)
// ---------------------------------------------------------------------------
__global__ __launch_bounds__(256) void k1_chunk(const float* __restrict__ kin,
                                                const float* __restrict__ vin,
                                                const short* __restrict__ Wb,
                                                const float* __restrict__ bias,
                                                float* __restrict__ SsT_g,
                                                float* __restrict__ zc_g,
                                                short* __restrict__ vT_g) {
    int c = blockIdx.x;
    const float* kc = kin + (size_t)c * CHK * DD;
    const float* vc = vin + (size_t)c * CHK * DD;

    __shared__ __align__(16) short KfT[DD][CHK + 8];   // [128][72] bf16, rows 144B (16-mult)
    __shared__ __align__(16) short vT [DD][CHK + 8];
    __shared__ __align__(16) float SsT[DD][DD + 4];    // [128][132] f32, rows 528B

    int tid = threadIdx.x, lane = tid & 63, w = tid >> 6;
    int l15 = lane & 15, l4 = lane >> 4;
    const f32x4 z4 = {0.f, 0.f, 0.f, 0.f};

    // ---- build vT (transpose v to bf16) ----
    #pragma unroll
    for (int it = 0; it < 8; ++it) {
        int i = tid + it * 256;                        // 2048 float4s
        int t = i >> 5, c4 = (i & 31) * 4;
        float4 vv = *(const float4*)(vc + t * DD + c4);
        vT[c4 + 0][t] = f2b(vv.x); vT[c4 + 1][t] = f2b(vv.y);
        vT[c4 + 2][t] = f2b(vv.z); vT[c4 + 3][t] = f2b(vv.w);
    }

    // ---- phi(k_c): wave w -> rows 16w..16w+15 ----
    {
        bf16x8 af[4];
        int row = 16 * w + l15;
        #pragma unroll
        for (int kk = 0; kk < 4; ++kk)
            af[kk] = cvt8(kc + row * DD + kk * 32 + l4 * 8);
        #pragma unroll
        for (int n = 0; n < 8; ++n) {
            int e = 16 * n + l15;
            f32x4 d = z4;
            #pragma unroll
            for (int kk = 0; kk < 4; ++kk) {
                bf16x8 bw = *(const bf16x8*)(Wb + e * DD + kk * 32 + l4 * 8);
                d = MFMA(af[kk], bw, d);
            }
            float bv = bias[e];
            #pragma unroll
            for (int j = 0; j < 4; ++j) {
                float zv = d[j] + bv;
                float r = (zv > 0.f) ? (zv + 1.f) : __expf(zv);   // ELU+1
                KfT[e][16 * w + l4 * 4 + j] = f2b(r);
            }
        }
    }
    __syncthreads();

    // ---- z_c[d] = sum_t Kf[t][d] ----
    if (tid < DD) {
        float s = 0.f;
        #pragma unroll
        for (int t8 = 0; t8 < CHK / 8; ++t8) {
            bf16x8 kv = *(const bf16x8*)&KfT[tid][t8 * 8];
            #pragma unroll
            for (int j = 0; j < 8; ++j) s += b2f(kv[j]);
        }
        zc_g[(size_t)c * DD + tid] = s;
    }

    // ---- store vT to global (for K3) ----
    #pragma unroll
    for (int it = 0; it < 4; ++it) {
        int i = tid + it * 256;                        // 1024 x 16B
        int e = i >> 3, t0 = (i & 7) * 8;
        *(bf16x8*)(vT_g + (size_t)c * DD * CHK + e * CHK + t0) = *(const bf16x8*)&vT[e][t0];
    }

    // ---- S-GEMM: S[d][e] = sum_t KfT[d][t] * v[t][e]; wave w -> d-tiles {2w,2w+1} ----
    {
        f32x4 sacc[2][8];
        #pragma unroll
        for (int mi = 0; mi < 2; ++mi)
            #pragma unroll
            for (int n = 0; n < 8; ++n) sacc[mi][n] = z4;
        #pragma unroll
        for (int kk = 0; kk < 2; ++kk) {
            bf16x8 afr[2];
            #pragma unroll
            for (int mi = 0; mi < 2; ++mi)
                afr[mi] = *(const bf16x8*)&KfT[16 * (2 * w + mi) + l15][kk * 32 + l4 * 8];
            #pragma unroll
            for (int n = 0; n < 8; ++n) {
                bf16x8 bfr = *(const bf16x8*)&vT[16 * n + l15][kk * 32 + l4 * 8];
                sacc[0][n] = MFMA(afr[0], bfr, sacc[0][n]);
                sacc[1][n] = MFMA(afr[1], bfr, sacc[1][n]);
            }
        }
        // D rows = d, cols = e -> SsT[e][d]
        #pragma unroll
        for (int mi = 0; mi < 2; ++mi)
            #pragma unroll
            for (int n = 0; n < 8; ++n) {
                int e = 16 * n + l15;
                #pragma unroll
                for (int j = 0; j < 4; ++j)
                    SsT[e][16 * (2 * w + mi) + l4 * 4 + j] = sacc[mi][n][j];
            }
    }
    __syncthreads();

    // ---- coalesced store SsT -> global [c][e][d] fp32 ----
    float* dst = SsT_g + (size_t)c * DD * DD;
    #pragma unroll
    for (int it = 0; it < 16; ++it) {
        int i = tid + it * 256;                        // 4096 float4s
        int e = i >> 5, c4 = (i & 31) * 4;
        *(float4*)(dst + e * DD + c4) = *(const float4*)&SsT[e][c4];
    }
}

// ---------------------------------------------------------------------------
// K2: exclusive prefix over chunks. grid 512 = (b,e) x 128 thr (thread = d).
//     Reads SsT fp32, writes SpT bf16. Blocks with e==0 also scan z.
// ---------------------------------------------------------------------------
__global__ __launch_bounds__(128) void k2_scan(const float* __restrict__ SsT_g,
                                               const float* __restrict__ zc_g,
                                               short* __restrict__ SpT_g,
                                               float* __restrict__ zp_g) {
    int e = blockIdx.x & 127, b = blockIdx.x >> 7;
    int d = threadIdx.x;
    size_t base = ((size_t)(b * NCHK) * DD + e) * DD + d;
    const size_t stride = (size_t)DD * DD;

    float vals[NCHK];
    #pragma unroll
    for (int c2 = 0; c2 < NCHK; ++c2) vals[c2] = SsT_g[base + c2 * stride];
    float run = 0.f;
    #pragma unroll
    for (int c2 = 0; c2 < NCHK; ++c2) {
        SpT_g[base + c2 * stride] = f2b(run);
        run += vals[c2];
    }

    if (e == 0) {
        float vz[NCHK];
        #pragma unroll
        for (int c2 = 0; c2 < NCHK; ++c2) vz[c2] = zc_g[(size_t)(b * NCHK + c2) * DD + d];
        float rz = 0.f;
        #pragma unroll
        for (int c2 = 0; c2 < NCHK; ++c2) {
            zp_g[(size_t)(b * NCHK + c2) * DD + d] = rz;
            rz += vz[c2];
        }
    }
}

// ---------------------------------------------------------------------------
// K3: per chunk: phi(q),phi(k) (MFMA, shared W-frags) -> LDS; P=QK^T masked ->
//     Ps bf16; den = rowsum(Ps)+Q.zpre+eps; out = Ps@V + Q@SpT; store fp32.
// grid 128 x 256 thr.
// ---------------------------------------------------------------------------
__global__ __launch_bounds__(256) void k3_out(const float* __restrict__ q,
                                              const float* __restrict__ kin,
                                              const short* __restrict__ Wb,
                                              const float* __restrict__ bias,
                                              const short* __restrict__ SpT_g,
                                              const float* __restrict__ zp_g,
                                              const short* __restrict__ vT_g,
                                              float* __restrict__ out) {
    int c = blockIdx.x;
    __shared__ __align__(16) short Qf[CHK][DD + 8];    // [64][136]
    __shared__ __align__(16) short Kf[CHK][DD + 8];
    __shared__ __align__(16) short Ps[CHK][CHK + 8];   // [64][72]
    __shared__ float zs[DD];
    __shared__ float den[CHK];

    int tid = threadIdx.x, lane = tid & 63, w = tid >> 6;
    int l15 = lane & 15, l4 = lane >> 4;
    const f32x4 z4 = {0.f, 0.f, 0.f, 0.f};

    if (tid < DD) zs[tid] = zp_g[(size_t)c * DD + tid];

    // ---- phi(q_c) and phi(k_c), sharing W fragments ----
    {
        const float* qc = q   + (size_t)c * CHK * DD;
        const float* kc = kin + (size_t)c * CHK * DD;
        bf16x8 afq[4], afk[4];
        int row = 16 * w + l15;
        #pragma unroll
        for (int kk = 0; kk < 4; ++kk) {
            afq[kk] = cvt8(qc + row * DD + kk * 32 + l4 * 8);
            afk[kk] = cvt8(kc + row * DD + kk * 32 + l4 * 8);
        }
        #pragma unroll
        for (int n = 0; n < 8; ++n) {
            int e = 16 * n + l15;
            f32x4 dq = z4, dk = z4;
            #pragma unroll
            for (int kk = 0; kk < 4; ++kk) {
                bf16x8 bw = *(const bf16x8*)(Wb + e * DD + kk * 32 + l4 * 8);
                dq = MFMA(afq[kk], bw, dq);
                dk = MFMA(afk[kk], bw, dk);
            }
            float bv = bias[e];
            #pragma unroll
            for (int j = 0; j < 4; ++j) {
                int t = 16 * w + l4 * 4 + j;
                float zq = dq[j] + bv;
                Qf[t][e] = f2b((zq > 0.f) ? (zq + 1.f) : __expf(zq));
                float zk = dk[j] + bv;
                Kf[t][e] = f2b((zk > 0.f) ? (zk + 1.f) : __expf(zk));
            }
        }
    }
    __syncthreads();

    // ---- QK^T (causal) -> Ps bf16 ----
    bf16x8 aq[4];
    #pragma unroll
    for (int kk = 0; kk < 4; ++kk)
        aq[kk] = *(const bf16x8*)&Qf[16 * w + l15][kk * 32 + l4 * 8];
    #pragma unroll
    for (int n2 = 0; n2 < 4; ++n2) {
        f32x4 p = z4;
        #pragma unroll
        for (int kk = 0; kk < 4; ++kk) {
            bf16x8 bk = *(const bf16x8*)&Kf[16 * n2 + l15][kk * 32 + l4 * 8];
            p = MFMA(aq[kk], bk, p);
        }
        int t2 = 16 * n2 + l15;
        #pragma unroll
        for (int j = 0; j < 4; ++j) {
            int t = 16 * w + l4 * 4 + j;
            Ps[t][t2] = (t2 <= t) ? f2b(p[j]) : (short)0;
        }
    }
    __syncthreads();

    // ---- den (wave 0) ----
    if (tid < CHK) {
        float s = 1e-6f;
        #pragma unroll
        for (int t8 = 0; t8 < CHK / 8; ++t8) {
            bf16x8 pv = *(const bf16x8*)&Ps[tid][t8 * 8];
            #pragma unroll
            for (int j = 0; j < 8; ++j) s += b2f(pv[j]);
        }
        #pragma unroll
        for (int d8 = 0; d8 < DD / 8; ++d8) {
            bf16x8 qv = *(const bf16x8*)&Qf[tid][d8 * 8];
            #pragma unroll
            for (int j = 0; j < 8; ++j) s += b2f(qv[j]) * zs[d8 * 8 + j];
        }
        den[tid] = s;
    }

    // ---- out = Ps @ V + Q @ Spre ----
    bf16x8 ap[2];
    #pragma unroll
    for (int kk = 0; kk < 2; ++kk)
        ap[kk] = *(const bf16x8*)&Ps[16 * w + l15][kk * 32 + l4 * 8];

    const short* Sp  = SpT_g + (size_t)c * DD * DD;
    const short* vTg = vT_g + (size_t)c * DD * CHK;
    f32x4 oacc[8];
    #pragma unroll
    for (int n = 0; n < 8; ++n) oacc[n] = z4;
    #pragma unroll
    for (int n = 0; n < 8; ++n) {
        int e = 16 * n + l15;
        #pragma unroll
        for (int kk = 0; kk < 4; ++kk) {
            bf16x8 bs = *(const bf16x8*)(Sp + e * DD + kk * 32 + l4 * 8);
            oacc[n] = MFMA(aq[kk], bs, oacc[n]);
        }
        #pragma unroll
        for (int kk = 0; kk < 2; ++kk) {
            bf16x8 bv = *(const bf16x8*)(vTg + e * CHK + kk * 32 + l4 * 8);
            oacc[n] = MFMA(ap[kk], bv, oacc[n]);
        }
    }
    __syncthreads();   // den ready

    float* oc = out + (size_t)c * CHK * DD;
    float invs[4];
    #pragma unroll
    for (int j = 0; j < 4; ++j) invs[j] = 1.0f / den[16 * w + l4 * 4 + j];
    #pragma unroll
    for (int n = 0; n < 8; ++n) {
        int e = 16 * n + l15;
        #pragma unroll
        for (int j = 0; j < 4; ++j) {
            int t = 16 * w + l4 * 4 + j;
            oc[t * DD + e] = oacc[n][j] * invs[j];
        }
    }
}

// ---------------------------------------------------------------------------
extern "C" void kernel_launch(void* const* d_in, const int* in_sizes, int n_in,
                              void* d_out, int out_size, void* d_ws, size_t ws_size,
                              hipStream_t stream) {
    const float* q  = (const float*)d_in[0];
    const float* k  = (const float*)d_in[1];
    const float* v  = (const float*)d_in[2];
    const float* W  = (const float*)d_in[3];
    const float* bi = (const float*)d_in[4];
    float* out = (float*)d_out;

    float* SsT_g = (float*)d_ws;                        // 128*128*128 f32 = 8 MB
    float* zc_g  = SsT_g + (size_t)NCHKS * DD * DD;     // 16384 f32
    float* zp_g  = zc_g + (size_t)NCHKS * DD;           // 16384 f32
    short* Wb    = (short*)(zp_g + (size_t)NCHKS * DD); // 16384 bf16
    short* SpT_g = Wb + DD * DD;                        // 128*128*128 bf16 = 4 MB
    short* vT_g  = SpT_g + (size_t)NCHKS * DD * DD;     // 128*128*64 bf16 = 2 MB

    k0_convw<<<16, 256, 0, stream>>>(W, Wb);
    k1_chunk<<<NCHKS, 256, 0, stream>>>(k, v, Wb, bi, SsT_g, zc_g, vT_g);
    k2_scan<<<512, 128, 0, stream>>>(SsT_g, zc_g, SpT_g, zp_g);
    k3_out<<<NCHKS, 256, 0, stream>>>(q, k, Wb, bi, SpT_g, zp_g, vT_g, out);
}